// Round 22
// baseline (555.753 us; speedup 1.0000x reference)
//
#include <hip/hip_runtime.h>
#include <hip/hip_bf16.h>

// Shapes (fixed by the problem)
#define BB 2
#define SS 1024
#define DD 1024
#define HH 16
#define DKV 64
#define EE 8
#define FF 2048
#define FSH2 4096

typedef __attribute__((ext_vector_type(8))) short bf16x8;   // 8 bf16 = 4 VGPR (MFMA A/B frag)
typedef __attribute__((ext_vector_type(4))) float f32x4;    // MFMA C/D frag

#define EPI_PLAIN 0
#define EPI_SCATTER 2
#define AM_DENSE 0
#define AM_GATHER 1
#define AM_GROUP 2

__device__ inline unsigned pack_bf2(float lo, float hi) {
    __hip_bfloat162 h = __float22bfloat162_rn(float2{lo, hi});
    union { __hip_bfloat162 h2; unsigned u; } c; c.h2 = h; return c.u;
}
__device__ inline unsigned short bf16_1(float x) {
    union { __hip_bfloat16 b; unsigned short u; } c;
    c.b = __float2bfloat16(x); return c.u;
}

// ------------------------------------------------------------------
// bf16-MFMA GEMM, 128x64 tile, BK=32, 256 threads (4 waves as 2x2).
// DEPTH-4 register pipeline + DOUBLE-BUFFERED LDS -> ONE barrier per
// K-step (the trailing buffer-protect barrier is gone: next stage goes
// to the other buffer; reads of buf[b] at iter it are lgkm-waited before
// that wave's barrier at it+1, and the next write to buf[b] is after
// everyone's barrier at it+1). B LDS layout [k-slot][col].
// ------------------------------------------------------------------
#define LOADT(s, k0) {                                                        \
    const float4* ap4 = (const float4*)(Ap + (k0));                           \
    pa##s##_0 = ap4[0]; pa##s##_1 = ap4[1];                                   \
    pa##s##_2 = ap4[2]; pa##s##_3 = ap4[3];                                   \
    const float* wp = Wcol + (size_t)((k0) + kg * 8) * N;                     \
    _Pragma("unroll")                                                         \
    for (int j = 0; j < 8; ++j) pb##s[j] = wp[(size_t)j * N];                 \
}
#define STAGET(s) {                                                           \
    unsigned short* Ab = As + (((s) & 1) * 5120);                             \
    unsigned short* Bb = Bs + (((s) & 1) * 2048);                             \
    uint4 aw0, aw1;                                                           \
    aw0.x = pack_bf2(pa##s##_0.x, pa##s##_0.y);                               \
    aw0.y = pack_bf2(pa##s##_0.z, pa##s##_0.w);                               \
    aw0.z = pack_bf2(pa##s##_1.x, pa##s##_1.y);                               \
    aw0.w = pack_bf2(pa##s##_1.z, pa##s##_1.w);                               \
    aw1.x = pack_bf2(pa##s##_2.x, pa##s##_2.y);                               \
    aw1.y = pack_bf2(pa##s##_2.z, pa##s##_2.w);                               \
    aw1.z = pack_bf2(pa##s##_3.x, pa##s##_3.y);                               \
    aw1.w = pack_bf2(pa##s##_3.z, pa##s##_3.w);                               \
    *(uint4*)&Ab[ar * 40 + ac] = aw0;                                         \
    *(uint4*)&Ab[ar * 40 + ac + 8] = aw1;                                     \
    uint4 bw;                                                                 \
    bw.x = pack_bf2(pb##s[0], pb##s[1]);  bw.y = pack_bf2(pb##s[2], pb##s[3]);\
    bw.z = pack_bf2(pb##s[4], pb##s[5]);  bw.w = pack_bf2(pb##s[6], pb##s[7]);\
    *(uint4*)&Bb[kg * 512 + bn * 8] = bw;                                     \
}
#define MFMAT(s) {                                                            \
    const unsigned short* Ab = As + (((s) & 1) * 5120);                       \
    const unsigned short* Bb = Bs + (((s) & 1) * 2048);                       \
    bf16x8 af[4], bfr[2];                                                     \
    _Pragma("unroll")                                                         \
    for (int m = 0; m < 4; ++m) {                                             \
        int row = wr * 64 + m * 16 + ll;                                      \
        af[m] = *(const bf16x8*)&Ab[row * 40 + lh * 8];                       \
    }                                                                         \
    _Pragma("unroll")                                                         \
    for (int n = 0; n < 2; ++n) {                                             \
        int col = wc * 32 + n * 16 + ll;                                      \
        bfr[n] = *(const bf16x8*)&Bb[lh * 512 + col * 8];                     \
    }                                                                         \
    _Pragma("unroll")                                                         \
    for (int m = 0; m < 4; ++m)                                               \
        _Pragma("unroll")                                                     \
        for (int n = 0; n < 2; ++n)                                           \
            acc[m][n] = __builtin_amdgcn_mfma_f32_16x16x32_bf16(af[m], bfr[n], acc[m][n], 0, 0, 0); \
}
#define PHASET(s, nx) {                                                       \
    STAGET(s)                                                                 \
    if ((nx) < NT) LOADT(s, (nx) << 5)                                        \
    asm volatile("s_waitcnt lgkmcnt(0)\n\ts_barrier" ::: "memory");           \
    MFMAT(s)                                                                  \
}

template<int EPI, int AMODE, int NSEL, int SPLITK>
__global__ __launch_bounds__(256, 2) void mgemm(
    const float* __restrict__ A,
    const float* __restrict__ W0, const float* __restrict__ W1p, const float* __restrict__ W2p,
    const float* __restrict__ b0, const float* __restrict__ b1p, const float* __restrict__ b2p,
    const float* __restrict__ addsrc,
    float* __restrict__ C0, float* __restrict__ C1p, float* __restrict__ C2p,
    int M, int N, int K,
    const int* __restrict__ tok_list, const int* __restrict__ cnt,
    const int* __restrict__ offs, const float* __restrict__ comb,
    const int* __restrict__ idx0, float* __restrict__ y1)
{
    __shared__ __align__(16) unsigned short As[2 * 128 * 40];   // 20 KB dbuf
    __shared__ __align__(16) unsigned short Bs[2 * 64 * 32];    // 8 KB dbuf
    __shared__ int rows_s[128];
    const int t = threadIdx.x;
    const float* W = W0; const float* bias = b0; float* C = C0;
    if (NSEL == 3) {
        if (blockIdx.z == 1) { W = W1p; bias = b1p; C = C1p; }
        else if (blockIdx.z == 2) { W = W2p; bias = b2p; C = C2p; }
    }
    const int e = (AMODE != AM_DENSE) ? blockIdx.z : 0;
    int ne = M, base = 0;
    if (AMODE != AM_DENSE) {
        ne = cnt[e];
        base = offs[e];
        if ((int)blockIdx.y * 128 >= ne) return;   // uniform exit, before any barrier
        W += (size_t)e * K * N;
        bias += (size_t)e * N;
    }
    const int m0 = blockIdx.y * 128;
    const int n0 = blockIdx.x * 64;
    if (AMODE == AM_GATHER) {
        if (t < 128) {
            int li = m0 + t; if (li >= ne) li = ne - 1;
            rows_s[t] = tok_list[e * 2048 + li];
        }
        __syncthreads();
    }
    const int ar = t >> 1;
    const int ac = (t & 1) * 16;
    const int bn = t & 63;          // B col within tile
    const int kg = t >> 6;          // B k-group (8 rows each)
    long arow;
    if (AMODE == AM_DENSE) arow = m0 + ar;
    else if (AMODE == AM_GATHER) arow = rows_s[ar];
    else { int li = m0 + ar; if (li >= ne) li = ne - 1; arow = base + li; }
    const int Kc = (SPLITK > 1) ? (K / SPLITK) : K;
    const size_t koff = (SPLITK > 1) ? (size_t)blockIdx.z * Kc : 0;
    const float* Ap = A + (size_t)arow * K + ac + koff;
    const float* Wcol = W + koff * N + n0 + bn;
    const int l = t & 63, w = t >> 6;
    const int wr = w >> 1, wc = w & 1;
    const int lh = l >> 4, ll = l & 15;
    f32x4 acc[4][2];
#pragma unroll
    for (int i = 0; i < 4; ++i)
#pragma unroll
        for (int j = 0; j < 2; ++j) acc[i][j] = f32x4{0.f, 0.f, 0.f, 0.f};

    const int NT = Kc >> 5;   // 8/32/64/128 for shapes used here: all % 4 == 0
    float4 pa0_0, pa0_1, pa0_2, pa0_3; float pb0[8];
    float4 pa1_0, pa1_1, pa1_2, pa1_3; float pb1[8];
    float4 pa2_0, pa2_1, pa2_2, pa2_3; float pb2[8];
    float4 pa3_0, pa3_1, pa3_2, pa3_3; float pb3[8];
    LOADT(0, 0)
    LOADT(1, 32)
    LOADT(2, 64)
    LOADT(3, 96)
    for (int it = 0; it < NT; it += 4) {
        PHASET(0, it + 4)
        PHASET(1, it + 5)
        PHASET(2, it + 6)
        PHASET(3, it + 7)
    }

#pragma unroll
    for (int m = 0; m < 4; ++m) {
#pragma unroll
        for (int n = 0; n < 2; ++n) {
            int colg = n0 + wc * 32 + n * 16 + ll;
            float bvv = (SPLITK > 1) ? 0.f : bias[colg];
#pragma unroll
            for (int j = 0; j < 4; ++j) {
                int li = m0 + wr * 64 + m * 16 + lh * 4 + j;
                float v = acc[m][n][j] + bvv;
                if (SPLITK > 1) {
                    C[(size_t)blockIdx.z * M * N + (size_t)li * N + colg] = v;
                } else if (EPI == EPI_PLAIN) {
                    if (AMODE == AM_DENSE) {
                        if (addsrc) v += addsrc[(size_t)li * N + colg];
                        C[(size_t)li * N + colg] = v;
                    } else {
                        if (li < ne) C[(size_t)(base + li) * N + colg] = v;
                    }
                } else {  // EPI_SCATTER (AM_GROUP)
                    if (li < ne) {
                        int tok = tok_list[e * 2048 + li];
                        float wgt = comb[tok * 8 + e];
                        float* dst = (idx0[tok] == e) ? C : y1;
                        dst[(size_t)tok * N + colg] = wgt * v;
                    }
                }
            }
        }
    }
}

// ------------------------------------------------------------------
// MERGED final GEMMs: z==0 -> shared-out sw2 (full K=4096, dense, writes sh);
// z==1..8 -> routed-out expert z-1 (K=2048, comb-weighted scatter to y0/y1).
// ------------------------------------------------------------------
__global__ __launch_bounds__(256, 2) void mgemmF(
    const float* __restrict__ Amid,   // routed mid
    const float* __restrict__ Smid,   // shared mid
    const float* __restrict__ W2r, const float* __restrict__ B2r,
    const float* __restrict__ W2s, const float* __restrict__ B2s,
    float* __restrict__ y0, float* __restrict__ y1, float* __restrict__ sh,
    const int* __restrict__ tok_list, const int* __restrict__ cnt,
    const int* __restrict__ offs, const float* __restrict__ comb,
    const int* __restrict__ idx0)
{
    __shared__ __align__(16) unsigned short As[2 * 128 * 40];   // 20 KB dbuf
    __shared__ __align__(16) unsigned short Bs[2 * 64 * 32];    // 8 KB dbuf
    const int t = threadIdx.x;
    const int z = blockIdx.z;
    const bool sh_mode = (z == 0);
    const int e = sh_mode ? 0 : (z - 1);
    const int N = DD;
    int K, ne, base;
    const float *A, *W, *bias;
    if (sh_mode) {
        K = FSH2; ne = 2048; base = 0;
        A = Smid; W = W2s; bias = B2s;
    } else {
        K = FF;
        ne = cnt[e];
        base = offs[e];
        if ((int)blockIdx.y * 128 >= ne) return;   // uniform exit
        A = Amid;
        W = W2r + (size_t)e * K * N;
        bias = B2r + (size_t)e * N;
    }
    const int m0 = blockIdx.y * 128;
    const int n0 = blockIdx.x * 64;
    const int ar = t >> 1;
    const int ac = (t & 1) * 16;
    const int bn = t & 63;
    const int kg = t >> 6;
    long arow;
    if (sh_mode) arow = m0 + ar;
    else { int li = m0 + ar; if (li >= ne) li = ne - 1; arow = base + li; }
    const float* Ap = A + (size_t)arow * K + ac;
    const float* Wcol = W + n0 + bn;
    const int l = t & 63, w = t >> 6;
    const int wr = w >> 1, wc = w & 1;
    const int lh = l >> 4, ll = l & 15;
    f32x4 acc[4][2];
#pragma unroll
    for (int i = 0; i < 4; ++i)
#pragma unroll
        for (int j = 0; j < 2; ++j) acc[i][j] = f32x4{0.f, 0.f, 0.f, 0.f};

    const int NT = K >> 5;   // 128 (shared) or 64 (routed): both % 4 == 0
    float4 pa0_0, pa0_1, pa0_2, pa0_3; float pb0[8];
    float4 pa1_0, pa1_1, pa1_2, pa1_3; float pb1[8];
    float4 pa2_0, pa2_1, pa2_2, pa2_3; float pb2[8];
    float4 pa3_0, pa3_1, pa3_2, pa3_3; float pb3[8];
    LOADT(0, 0)
    LOADT(1, 32)
    LOADT(2, 64)
    LOADT(3, 96)
    for (int it = 0; it < NT; it += 4) {
        PHASET(0, it + 4)
        PHASET(1, it + 5)
        PHASET(2, it + 6)
        PHASET(3, it + 7)
    }

#pragma unroll
    for (int m = 0; m < 4; ++m) {
#pragma unroll
        for (int n = 0; n < 2; ++n) {
            int colg = n0 + wc * 32 + n * 16 + ll;
            float bvv = bias[colg];
#pragma unroll
            for (int j = 0; j < 4; ++j) {
                int li = m0 + wr * 64 + m * 16 + lh * 4 + j;
                float v = acc[m][n][j] + bvv;
                if (sh_mode) {
                    sh[(size_t)li * N + colg] = v;
                } else {
                    if (li < ne) {
                        int tok = tok_list[e * 2048 + li];
                        float wgt = comb[tok * 8 + e];
                        float* dst = (idx0[tok] == e) ? y0 : y1;
                        dst[(size_t)tok * N + colg] = wgt * v;
                    }
                }
            }
        }
    }
}

// ------------------------------------------------------------------
// FUSED dual-B silu GEMM at BN=64: Out = silu(A@W1+b1)*(A@W3+b3).
// DEPTH-2 register pipeline + DOUBLE-BUFFERED LDS (one barrier/K-step).
// ------------------------------------------------------------------
#define LOAD2T(s, k0) {                                                       \
    const float4* ap4 = (const float4*)(Ap + (k0));                           \
    pa##s##_0 = ap4[0]; pa##s##_1 = ap4[1];                                   \
    pa##s##_2 = ap4[2]; pa##s##_3 = ap4[3];                                   \
    const float* wp1 = W1col + (size_t)((k0) + kg * 8) * N;                   \
    const float* wp3 = W3col + (size_t)((k0) + kg * 8) * N;                   \
    _Pragma("unroll")                                                         \
    for (int j = 0; j < 8; ++j) {                                             \
        pb1##s[j] = wp1[(size_t)j * N];                                       \
        pb3##s[j] = wp3[(size_t)j * N];                                       \
    }                                                                         \
}
#define STAGE2T(s) {                                                          \
    unsigned short* Ab  = As  + ((s) * 5120);                                 \
    unsigned short* B1b = B1s + ((s) * 2048);                                 \
    unsigned short* B3b = B3s + ((s) * 2048);                                 \
    uint4 aw0, aw1;                                                           \
    aw0.x = pack_bf2(pa##s##_0.x, pa##s##_0.y);                               \
    aw0.y = pack_bf2(pa##s##_0.z, pa##s##_0.w);                               \
    aw0.z = pack_bf2(pa##s##_1.x, pa##s##_1.y);                               \
    aw0.w = pack_bf2(pa##s##_1.z, pa##s##_1.w);                               \
    aw1.x = pack_bf2(pa##s##_2.x, pa##s##_2.y);                               \
    aw1.y = pack_bf2(pa##s##_2.z, pa##s##_2.w);                               \
    aw1.z = pack_bf2(pa##s##_3.x, pa##s##_3.y);                               \
    aw1.w = pack_bf2(pa##s##_3.z, pa##s##_3.w);                               \
    *(uint4*)&Ab[ar * 40 + ac] = aw0;                                         \
    *(uint4*)&Ab[ar * 40 + ac + 8] = aw1;                                     \
    uint4 bw;                                                                 \
    bw.x = pack_bf2(pb1##s[0], pb1##s[1]);  bw.y = pack_bf2(pb1##s[2], pb1##s[3]); \
    bw.z = pack_bf2(pb1##s[4], pb1##s[5]);  bw.w = pack_bf2(pb1##s[6], pb1##s[7]); \
    *(uint4*)&B1b[kg * 512 + bn * 8] = bw;                                    \
    bw.x = pack_bf2(pb3##s[0], pb3##s[1]);  bw.y = pack_bf2(pb3##s[2], pb3##s[3]); \
    bw.z = pack_bf2(pb3##s[4], pb3##s[5]);  bw.w = pack_bf2(pb3##s[6], pb3##s[7]); \
    *(uint4*)&B3b[kg * 512 + bn * 8] = bw;                                    \
}
#define MFMA2T(s) {                                                           \
    const unsigned short* Ab  = As  + ((s) * 5120);                           \
    const unsigned short* B1b = B1s + ((s) * 2048);                           \
    const unsigned short* B3b = B3s + ((s) * 2048);                           \
    bf16x8 af[4], bfr[2];                                                     \
    _Pragma("unroll")                                                         \
    for (int m = 0; m < 4; ++m) {                                             \
        int row = wr * 64 + m * 16 + ll;                                      \
        af[m] = *(const bf16x8*)&Ab[row * 40 + lh * 8];                       \
    }                                                                         \
    _Pragma("unroll")                                                         \
    for (int n = 0; n < 2; ++n) {                                             \
        int col = wc * 32 + n * 16 + ll;                                      \
        bfr[n] = *(const bf16x8*)&B1b[lh * 512 + col * 8];                    \
    }                                                                         \
    _Pragma("unroll")                                                         \
    for (int m = 0; m < 4; ++m)                                               \
        _Pragma("unroll")                                                     \
        for (int n = 0; n < 2; ++n)                                           \
            acc1[m][n] = __builtin_amdgcn_mfma_f32_16x16x32_bf16(af[m], bfr[n], acc1[m][n], 0, 0, 0); \
    _Pragma("unroll")                                                         \
    for (int n = 0; n < 2; ++n) {                                             \
        int col = wc * 32 + n * 16 + ll;                                      \
        bfr[n] = *(const bf16x8*)&B3b[lh * 512 + col * 8];                    \
    }                                                                         \
    _Pragma("unroll")                                                         \
    for (int m = 0; m < 4; ++m)                                               \
        _Pragma("unroll")                                                     \
        for (int n = 0; n < 2; ++n)                                           \
            acc3[m][n] = __builtin_amdgcn_mfma_f32_16x16x32_bf16(af[m], bfr[n], acc3[m][n], 0, 0, 0); \
}
#define PHASE2T(s, nx) {                                                      \
    STAGE2T(s)                                                                \
    if ((nx) < NT) LOAD2T(s, (nx) << 5)                                       \
    asm volatile("s_waitcnt lgkmcnt(0)\n\ts_barrier" ::: "memory");           \
    MFMA2T(s)                                                                 \
}

#define MGEMM2_BODY(GATED) {                                                  \
    const int l = t & 63, w = t >> 6;                                         \
    const int wr = w >> 1, wc = w & 1;                                        \
    const int lh = l >> 4, ll = l & 15;                                       \
    f32x4 acc1[4][2], acc3[4][2];                                             \
    _Pragma("unroll")                                                         \
    for (int i = 0; i < 4; ++i)                                               \
        _Pragma("unroll")                                                     \
        for (int j = 0; j < 2; ++j) {                                         \
            acc1[i][j] = f32x4{0.f, 0.f, 0.f, 0.f};                           \
            acc3[i][j] = f32x4{0.f, 0.f, 0.f, 0.f};                           \
        }                                                                     \
    const int NT = K >> 5;                                                    \
    float4 pa0_0, pa0_1, pa0_2, pa0_3; float pb10[8], pb30[8];                \
    float4 pa1_0, pa1_1, pa1_2, pa1_3; float pb11[8], pb31[8];                \
    LOAD2T(0, 0)                                                              \
    LOAD2T(1, 32)                                                             \
    for (int it = 0; it < NT; it += 2) {                                      \
        PHASE2T(0, it + 2)                                                    \
        PHASE2T(1, it + 3)                                                    \
    }                                                                         \
    _Pragma("unroll")                                                         \
    for (int m = 0; m < 4; ++m) {                                             \
        _Pragma("unroll")                                                     \
        for (int n = 0; n < 2; ++n) {                                         \
            int colg = n0 + wc * 32 + n * 16 + ll;                            \
            float bv1 = b1[colg], bv3 = b3[colg];                             \
            _Pragma("unroll")                                                 \
            for (int j = 0; j < 4; ++j) {                                     \
                int li = m0 + wr * 64 + m * 16 + lh * 4 + j;                  \
                if (GATED && li >= ne) continue;                              \
                float a = acc1[m][n][j] + bv1;                                \
                float g = acc3[m][n][j] + bv3;                                \
                float sil = a / (1.0f + __expf(-a));                          \
                size_t off = (size_t)(base + li) * N + colg;                  \
                Out[off] = sil * g;                                           \
            }                                                                 \
        }                                                                     \
    }                                                                         \
}

template<int AMODE>
__global__ __launch_bounds__(256, 2) void mgemm2(
    const float* __restrict__ A,
    const float* __restrict__ W1, const float* __restrict__ W3,
    const float* __restrict__ B1, const float* __restrict__ B3,
    float* __restrict__ Out, int M, int N, int K,
    const int* __restrict__ tok_list, const int* __restrict__ cnt,
    const int* __restrict__ offs)
{
    __shared__ __align__(16) unsigned short As[2 * 128 * 40];   // 20 KB dbuf
    __shared__ __align__(16) unsigned short B1s[2 * 64 * 32];   // 8 KB dbuf
    __shared__ __align__(16) unsigned short B3s[2 * 64 * 32];   // 8 KB dbuf
    __shared__ int rows_s[128];
    const int t = threadIdx.x;
    const int e = (AMODE == AM_GATHER) ? blockIdx.z : 0;
    int ne = M, base = 0;
    const float *w1 = W1, *w3 = W3, *b1 = B1, *b3 = B3;
    if (AMODE == AM_GATHER) {
        ne = cnt[e];
        base = offs[e];
        if ((int)blockIdx.y * 128 >= ne) return;   // uniform exit
        w1 += (size_t)e * K * N; w3 += (size_t)e * K * N;
        b1 += (size_t)e * N;     b3 += (size_t)e * N;
    }
    const int m0 = blockIdx.y * 128;
    const int n0 = blockIdx.x * 64;
    if (AMODE == AM_GATHER) {
        if (t < 128) {
            int li = m0 + t; if (li >= ne) li = ne - 1;
            rows_s[t] = tok_list[e * 2048 + li];
        }
        __syncthreads();
    }
    const int ar = t >> 1;
    const int ac = (t & 1) * 16;
    const int bn = t & 63;
    const int kg = t >> 6;
    long arow = (AMODE == AM_GATHER) ? (long)rows_s[ar] : (long)(m0 + ar);
    const float* Ap = A + (size_t)arow * K + ac;
    const float* W1col = w1 + n0 + bn;
    const float* W3col = w3 + n0 + bn;
    if (AMODE == AM_GATHER) { MGEMM2_BODY(1) } else { MGEMM2_BODY(0) }
}

// MERGED routed+shared silu GEMM: z<8 -> routed expert z (x<FF/64 only),
// z==8 -> shared dense (full x).
__global__ __launch_bounds__(256, 2) void mgemm2m(
    const float* __restrict__ A,
    const float* __restrict__ W1r, const float* __restrict__ W3r,
    const float* __restrict__ B1r, const float* __restrict__ B3r,
    const float* __restrict__ W1sh, const float* __restrict__ W3sh,
    const float* __restrict__ B1sh, const float* __restrict__ B3sh,
    float* __restrict__ OutR, float* __restrict__ OutS, int K,
    const int* __restrict__ tok_list, const int* __restrict__ cnt,
    const int* __restrict__ offs)
{
    __shared__ __align__(16) unsigned short As[2 * 128 * 40];   // 20 KB dbuf
    __shared__ __align__(16) unsigned short B1s[2 * 64 * 32];   // 8 KB dbuf
    __shared__ __align__(16) unsigned short B3s[2 * 64 * 32];   // 8 KB dbuf
    __shared__ int rows_s[128];
    const int t = threadIdx.x;
    const int z = blockIdx.z;
    const bool routed = (z < 8);
    int N, ne, base;
    const float *w1, *w3, *b1, *b3;
    float* Out;
    if (routed) {
        if ((int)blockIdx.x >= FF / 64) return;       // uniform
        N = FF;
        ne = cnt[z];
        base = offs[z];
        if ((int)blockIdx.y * 128 >= ne) return;      // uniform
        w1 = W1r + (size_t)z * K * N; w3 = W3r + (size_t)z * K * N;
        b1 = B1r + (size_t)z * N;     b3 = B3r + (size_t)z * N;
        Out = OutR;
    } else {
        N = FSH2;
        ne = 2048;
        base = 0;
        w1 = W1sh; w3 = W3sh; b1 = B1sh; b3 = B3sh;
        Out = OutS;
    }
    const int m0 = blockIdx.y * 128;
    const int n0 = blockIdx.x * 64;
    if (routed) {
        if (t < 128) {
            int li = m0 + t; if (li >= ne) li = ne - 1;
            rows_s[t] = tok_list[z * 2048 + li];
        }
        __syncthreads();
    }
    const int ar = t >> 1;
    const int ac = (t & 1) * 16;
    const int bn = t & 63;
    const int kg = t >> 6;
    long arow = routed ? (long)rows_s[ar] : (long)(m0 + ar);
    const float* Ap = A + (size_t)arow * K + ac;
    const float* W1col = w1 + n0 + bn;
    const float* W3col = w3 + n0 + bn;
    if (routed) { MGEMM2_BODY(1) } else { MGEMM2_BODY(0) }
}

// ---------------------------------------------------------------- FUSED reduce + LayerNorm
// Block b == row b (256 threads x float4 = 1024 floats). Partial-sum order
// identical to the old reducek; ln reduction identical to ln_kernel ->
// bit-identical x2 and hn. Saves one launch + an 8MB x2 re-read.
__global__ __launch_bounds__(256) void reduceln(const float* __restrict__ P, int ns,
                                                const float* __restrict__ bias,
                                                const float* __restrict__ addsrc,
                                                float* __restrict__ x2out,
                                                const float* __restrict__ lw,
                                                float* __restrict__ hnout) {
    __shared__ float red[4], red2[4];
    const int row = blockIdx.x;
    const int t = threadIdx.x;
    size_t i = (size_t)row * 256 + t;                 // float4 index (N=1024)
    const size_t MN4 = (size_t)2048 * 256;
    float4 s = ((const float4*)P)[i];
    for (int sl = 1; sl < ns; ++sl) {
        float4 p = ((const float4*)P)[i + (size_t)sl * MN4];
        s.x += p.x; s.y += p.y; s.z += p.z; s.w += p.w;
    }
    float4 b = ((const float4*)bias)[t];
    s.x += b.x; s.y += b.y; s.z += b.z; s.w += b.w;
    float4 a = ((const float4*)addsrc)[i];
    s.x += a.x; s.y += a.y; s.z += a.z; s.w += a.w;
    ((float4*)x2out)[i] = s;
    // layernorm on s (same reduction tree as ln_kernel)
    float sum = s.x + s.y + s.z + s.w;
    float q = s.x * s.x + s.y * s.y + s.z * s.z + s.w * s.w;
    for (int o = 32; o; o >>= 1) { sum += __shfl_down(sum, o); q += __shfl_down(q, o); }
    if ((t & 63) == 0) { red[t >> 6] = sum; red2[t >> 6] = q; }
    __syncthreads();
    float S = red[0] + red[1] + red[2] + red[3];
    float Q = red2[0] + red2[1] + red2[2] + red2[3];
    float mu = S * (1.0f / DD);
    float var = Q * (1.0f / DD) - mu * mu;
    float inv = rsqrtf(var + 1e-8f);
    float4 wv = ((const float4*)lw)[t];
    float4 o4;
    o4.x = (s.x - mu) * inv * wv.x;
    o4.y = (s.y - mu) * inv * wv.y;
    o4.z = (s.z - mu) * inv * wv.z;
    o4.w = (s.w - mu) * inv * wv.w;
    ((float4*)(hnout + (size_t)row * DD))[t] = o4;
}

// ---------------------------------------------------------------- LayerNorm
__global__ __launch_bounds__(256) void ln_kernel(const float* __restrict__ x,
                                                 const float* __restrict__ w,
                                                 float* __restrict__ y) {
    __shared__ float red[4], red2[4];
    const int row = blockIdx.x;
    const int t = threadIdx.x;
    const float4* xr = (const float4*)(x + (size_t)row * DD);
    float4 v = xr[t];
    float s = v.x + v.y + v.z + v.w;
    float q = v.x * v.x + v.y * v.y + v.z * v.z + v.w * v.w;
    for (int o = 32; o; o >>= 1) { s += __shfl_down(s, o); q += __shfl_down(q, o); }
    if ((t & 63) == 0) { red[t >> 6] = s; red2[t >> 6] = q; }
    __syncthreads();
    float S = red[0] + red[1] + red[2] + red[3];
    float Q = red2[0] + red2[1] + red2[2] + red2[3];
    float mu = S * (1.0f / DD);
    float var = Q * (1.0f / DD) - mu * mu;
    float inv = rsqrtf(var + 1e-8f);
    const float4* wr = (const float4*)w;
    float4 wv = wr[t];
    float4 o4;
    o4.x = (v.x - mu) * inv * wv.x;
    o4.y = (v.y - mu) * inv * wv.y;
    o4.z = (v.z - mu) * inv * wv.z;
    o4.w = (v.w - mu) * inv * wv.w;
    ((float4*)(y + (size_t)row * DD))[t] = o4;
}

// ---------------------------------------------------------------- MFMA flash attention
// Q-tile 64 rows (wave owns 16): grid = (SS/64, B*H) = 512 blocks -> 2/CU.
__global__ __launch_bounds__(256) void attn_mfma(const float* __restrict__ Q,
                                                 const float* __restrict__ Kk,
                                                 const float* __restrict__ V,
                                                 const float* __restrict__ pe,
                                                 const float* __restrict__ mask,
                                                 const int* __restrict__ sp_ptr,
                                                 float* __restrict__ O) {
    __shared__ __align__(16) unsigned short Kt[64 * 64];    // 8 KB
    __shared__ __align__(16) unsigned short Vt[64 * 64];    // 8 KB
    __shared__ __align__(16) unsigned short Pl[4][16 * 64]; // 8 KB (16 rows/wave)
    const int t = threadIdx.x;
    const int w = t >> 6, l = t & 63;
    const int ll = l & 15, lh = l >> 4;
    const int bh = blockIdx.y;
    const int b = bh >> 4, h = bh & 15;
    const int q0 = blockIdx.x * 64;
    const int sp = sp_ptr[0];

    bf16x8 qf[2];
    {
        const float* qp = Q + (size_t)(b * SS + q0 + w * 16 + ll) * DD + h * 64 + lh * 8;
#pragma unroll
        for (int kk = 0; kk < 2; ++kk) {
            float4 x0 = *(const float4*)(qp + kk * 32);
            float4 x1 = *(const float4*)(qp + kk * 32 + 4);
            uint4 u;
            u.x = pack_bf2(x0.x * 0.125f, x0.y * 0.125f);
            u.y = pack_bf2(x0.z * 0.125f, x0.w * 0.125f);
            u.z = pack_bf2(x1.x * 0.125f, x1.y * 0.125f);
            u.w = pack_bf2(x1.z * 0.125f, x1.w * 0.125f);
            qf[kk] = *(bf16x8*)&u;
        }
    }
    f32x4 oacc[4];
#pragma unroll
    for (int n = 0; n < 4; ++n) oacc[n] = f32x4{0.f, 0.f, 0.f, 0.f};
    float mrun[4], lrun[4];
#pragma unroll
    for (int j = 0; j < 4; ++j) { mrun[j] = -3.0e38f; lrun[j] = 0.f; }

    const size_t pebase = (size_t)h * SS * SS + (size_t)sp;

    for (int kt0 = 0; kt0 < SS; kt0 += 64) {
        __syncthreads();
        {
            const int key = t >> 2, dg = (t & 3) * 16;
            const float* kp = Kk + (size_t)(b * SS + kt0 + key) * DD + h * 64 + dg;
            float4 k0 = *(const float4*)kp, k1 = *(const float4*)(kp + 4);
            float4 k2 = *(const float4*)(kp + 8), k3 = *(const float4*)(kp + 12);
            uint4 u0, u1;
            u0.x = pack_bf2(k0.x, k0.y); u0.y = pack_bf2(k0.z, k0.w);
            u0.z = pack_bf2(k1.x, k1.y); u0.w = pack_bf2(k1.z, k1.w);
            u1.x = pack_bf2(k2.x, k2.y); u1.y = pack_bf2(k2.z, k2.w);
            u1.z = pack_bf2(k3.x, k3.y); u1.w = pack_bf2(k3.z, k3.w);
            const int sw = (key & 7) << 4;
            *(uint4*)((char*)Kt + key * 128 + ((dg * 2) ^ sw)) = u0;
            *(uint4*)((char*)Kt + key * 128 + ((dg * 2 + 16) ^ sw)) = u1;
        }
        {
            const int kp2 = t & 31, vg = (t >> 5) * 8;
            const float* vp0 = V + (size_t)(b * SS + kt0 + 2 * kp2) * DD + h * 64 + vg;
            const float* vp1 = vp0 + DD;
            float4 a0 = *(const float4*)vp0, a1 = *(const float4*)(vp0 + 4);
            float4 b0 = *(const float4*)vp1, b1 = *(const float4*)(vp1 + 4);
            float va[8] = {a0.x, a0.y, a0.z, a0.w, a1.x, a1.y, a1.z, a1.w};
            float vb[8] = {b0.x, b0.y, b0.z, b0.w, b1.x, b1.y, b1.z, b1.w};
#pragma unroll
            for (int j = 0; j < 8; ++j) {
                int vd = vg + j;
                unsigned u = pack_bf2(va[j], vb[j]);
                *(unsigned*)((char*)Vt + vd * 128 + ((kp2 * 4) ^ ((vd & 7) << 4))) = u;
            }
        }
        __syncthreads();
        f32x4 sc[4];
#pragma unroll
        for (int n = 0; n < 4; ++n) sc[n] = f32x4{0.f, 0.f, 0.f, 0.f};
#pragma unroll
        for (int n = 0; n < 4; ++n) {
            const int key = n * 16 + ll;
            const int sw = (key & 7) << 4;
#pragma unroll
            for (int kk = 0; kk < 2; ++kk) {
                bf16x8 kf = *(const bf16x8*)((char*)Kt + key * 128 + ((kk * 64 + lh * 16) ^ sw));
                sc[n] = __builtin_amdgcn_mfma_f32_16x16x32_bf16(qf[kk], kf, sc[n], 0, 0, 0);
            }
        }
#pragma unroll
        for (int j = 0; j < 4; ++j) {
            const int qrow = q0 + w * 16 + lh * 4 + j;
            const float* per = pe + pebase + (size_t)(sp + qrow) * SS + kt0 + ll;
            const float* mar = mask + (size_t)qrow * SS + kt0 + ll;
#pragma unroll
            for (int n = 0; n < 4; ++n)
                sc[n][j] += per[n * 16] + mar[n * 16];
        }
#pragma unroll
        for (int j = 0; j < 4; ++j) {
            float mx = fmaxf(fmaxf(sc[0][j], sc[1][j]), fmaxf(sc[2][j], sc[3][j]));
#pragma unroll
            for (int o = 1; o < 16; o <<= 1) mx = fmaxf(mx, __shfl_xor(mx, o));
            float mnew = fmaxf(mrun[j], mx);
            float corr = __expf(mrun[j] - mnew);
            mrun[j] = mnew;
            float ssum = 0.f;
#pragma unroll
            for (int n = 0; n < 4; ++n) {
                float p = __expf(sc[n][j] - mnew);
                sc[n][j] = p;
                ssum += p;
            }
#pragma unroll
            for (int o = 1; o < 16; o <<= 1) ssum += __shfl_xor(ssum, o);
            lrun[j] = lrun[j] * corr + ssum;
#pragma unroll
            for (int n = 0; n < 4; ++n) oacc[n][j] *= corr;
        }
#pragma unroll
        for (int j = 0; j < 4; ++j) {
            const int lq = lh * 4 + j;
            const int sw = (lq & 7) << 4;
#pragma unroll
            for (int n = 0; n < 4; ++n) {
                const int key = n * 16 + ll;
                *(unsigned short*)((char*)Pl[w] + lq * 128 + ((key * 2) ^ sw)) =
                    bf16_1(sc[n][j]);
            }
        }
        asm volatile("s_waitcnt lgkmcnt(0)" ::: "memory");
        __builtin_amdgcn_sched_barrier(0);
#pragma unroll
        for (int kk = 0; kk < 2; ++kk) {
            const int lq = ll;
            bf16x8 pf = *(const bf16x8*)((char*)Pl[w] + lq * 128 +
                                         ((kk * 64 + lh * 16) ^ ((lq & 7) << 4)));
#pragma unroll
            for (int n = 0; n < 4; ++n) {
                const int vd = n * 16 + ll;
                bf16x8 vf = *(const bf16x8*)((char*)Vt + vd * 128 +
                                             ((kk * 64 + lh * 16) ^ ((vd & 7) << 4)));
                oacc[n] = __builtin_amdgcn_mfma_f32_16x16x32_bf16(pf, vf, oacc[n], 0, 0, 0);
            }
        }
    }
#pragma unroll
    for (int j = 0; j < 4; ++j) {
        const int qrow = q0 + w * 16 + lh * 4 + j;
        const float invl = 1.0f / lrun[j];
#pragma unroll
        for (int n = 0; n < 4; ++n)
            O[(size_t)(b * SS + qrow) * DD + h * 64 + n * 16 + ll] = oacc[n][j] * invl;
    }
}

// ---------------------------------------------------------------- Gating (f32 path)
__global__ __launch_bounds__(64) void gate_kernel(const float* __restrict__ hn,
                                                  const float* __restrict__ gw,
                                                  const float* __restrict__ gb,
                                                  float* __restrict__ comb,
                                                  int* __restrict__ idx0,
                                                  int* __restrict__ cnt,
                                                  int* __restrict__ tok_list) {
    __shared__ float lg[8];
    const int tok = blockIdx.x;
    const int lane = threadIdx.x;
    const int e = lane >> 3, chunk = lane & 7;
    const float* hr = hn + (size_t)tok * DD + chunk * 128;
    const float* gr = gw + (size_t)e * DD + chunk * 128;
    float p = 0.f;
    for (int j = 0; j < 128; ++j) p += hr[j] * gr[j];
    p += __shfl_down(p, 4, 8);
    p += __shfl_down(p, 2, 8);
    p += __shfl_down(p, 1, 8);
    if (chunk == 0) lg[e] = p + gb[e];
    __syncthreads();
    if (lane == 0) {
        float mx = lg[0];
        for (int i = 1; i < 8; ++i) mx = fmaxf(mx, lg[i]);
        float pr[8]; float ssum = 0.f;
        for (int i = 0; i < 8; ++i) { pr[i] = __expf(lg[i] - mx); ssum += pr[i]; }
        float is = 1.0f / ssum;
        for (int i = 0; i < 8; ++i) pr[i] *= is;
        int i1 = 0;
        for (int i = 1; i < 8; ++i) if (pr[i] > pr[i1]) i1 = i;
        int i2 = -1;
        for (int i = 0; i < 8; ++i) { if (i == i1) continue; if (i2 < 0 || pr[i] > pr[i2]) i2 = i; }
        float w0 = pr[i1], w1 = pr[i2];
        float nrm = 1.0f / (w0 + w1 + 1e-20f);
        w0 *= nrm; w1 *= nrm;
        for (int i = 0; i < 8; ++i) comb[tok * 8 + i] = 0.0f;
        comb[tok * 8 + i1] = w0;
        comb[tok * 8 + i2] = w1;
        idx0[tok] = i1;
        int s1 = atomicAdd(&cnt[i1], 1); tok_list[i1 * 2048 + s1] = tok;
        int s2 = atomicAdd(&cnt[i2], 1); tok_list[i2 * 2048 + s2] = tok;
    }
}

__global__ void init_cnt(int* cnt) { if (threadIdx.x < 8) cnt[threadIdx.x] = 0; }

__global__ void prefix_kernel(const int* __restrict__ cnt, int* __restrict__ offs) {
    if (threadIdx.x == 0) {
        int a = 0;
        for (int e = 0; e < 8; ++e) { offs[e] = a; a += cnt[e]; }
    }
}

// ---------------------------------------------------------------- Final sum
__global__ __launch_bounds__(256) void final_kernel(const float* __restrict__ x2,
                                                    const float* __restrict__ y0,
                                                    const float* __restrict__ y1,
                                                    const float* __restrict__ sh,
                                                    float* __restrict__ out) {
    size_t i = (size_t)blockIdx.x * 256 + threadIdx.x;
    float4 a = ((const float4*)x2)[i];
    float4 b = ((const float4*)y0)[i];
    float4 c = ((const float4*)y1)[i];
    float4 d = ((const float4*)sh)[i];
    float4 o;
    o.x = a.x + b.x + c.x + d.x;
    o.y = a.y + b.y + c.y + d.y;
    o.z = a.z + b.z + c.z + d.z;
    o.w = a.w + b.w + c.w + d.w;
    ((float4*)out)[i] = o;
}

#define NUL6 nullptr, nullptr, nullptr, nullptr, nullptr, nullptr

extern "C" void kernel_launch(void* const* d_in, const int* in_sizes, int n_in,
                              void* d_out, int out_size, void* d_ws, size_t ws_size,
                              hipStream_t stream) {
    const float* x   = (const float*)d_in[0];
    const int*   sp  = (const int*)d_in[1];
    const float* mask= (const float*)d_in[2];
    const float* pe  = (const float*)d_in[3];
    const float* anw = (const float*)d_in[4];
    const float* fnw = (const float*)d_in[5];
    const float* wq  = (const float*)d_in[6];  const float* bq  = (const float*)d_in[7];
    const float* wk  = (const float*)d_in[8];  const float* bk  = (const float*)d_in[9];
    const float* wv  = (const float*)d_in[10]; const float* bv  = (const float*)d_in[11];
    const float* wo  = (const float*)d_in[12]; const float* bo  = (const float*)d_in[13];
    const float* gw  = (const float*)d_in[14]; const float* gb  = (const float*)d_in[15];
    const float* ew1 = (const float*)d_in[16]; const float* eb1 = (const float*)d_in[17];
    const float* ew2 = (const float*)d_in[18]; const float* eb2 = (const float*)d_in[19];
    const float* ew3 = (const float*)d_in[20]; const float* eb3 = (const float*)d_in[21];
    const float* sw1 = (const float*)d_in[22]; const float* sb1 = (const float*)d_in[23];
    const float* sw2 = (const float*)d_in[24]; const float* sb2 = (const float*)d_in[25];
    const float* sw3 = (const float*)d_in[26]; const float* sb3 = (const float*)d_in[27];

    float* ws = (float*)d_ws;
    const size_t M2 = (size_t)2048 * 1024;   // 8 MB (2M floats) per slot
    float* comb = ws;                        // 2048*8
    int* idx0   = (int*)(ws + 16384);        // 2048
    int* cnt    = idx0 + 2048;
    int* offs   = cnt + 8;
    int* tok_list = offs + 8;                // 8*2048
    float* base = ws + 65536;
    float* xn   = base;
    float* q    = base + 1 * M2;
    float* kbuf = base + 2 * M2;
    float* vbuf = base + 3 * M2;
    float* x2   = base + 4 * M2;
    float* amid = base + 5 * M2;             // wo partials -> routed mid (slots 5-8)
    float* smid = base + 9 * M2;             // shared mid (slots 9-12, big path)
    const bool big = ws_size >= (size_t)(65536 + 13 * M2) * sizeof(float);
    float* o   = xn;
    float* hn  = q;
    float* y0  = xn;
    float* y1  = kbuf;
    float* sh  = vbuf;

    ln_kernel<<<2048, 256, 0, stream>>>(x, anw, xn);
    // QKV in one dispatch (z selects W/bias/C)
    mgemm<EPI_PLAIN, AM_DENSE, 3, 1><<<dim3(16, 16, 3), 256, 0, stream>>>(
        xn, wq, wk, wv, bq, bk, bv, nullptr, q, kbuf, vbuf,
        2048, 1024, 1024, NUL6);
    attn_mfma<<<dim3(SS / 64, BB * HH), 256, 0, stream>>>(q, kbuf, vbuf, pe, mask, sp, o);
    // wo: split-K4 into amid (free here), then FUSED reduce+residual+layernorm
    mgemm<EPI_PLAIN, AM_DENSE, 1, 4><<<dim3(16, 16, 4), 256, 0, stream>>>(
        o, wo, nullptr, nullptr, bo, nullptr, nullptr, nullptr, amid, nullptr, nullptr,
        2048, 1024, 1024, NUL6);
    reduceln<<<2048, 256, 0, stream>>>(amid, 4, bo, x, x2, fnw, hn);
    init_cnt<<<1, 64, 0, stream>>>(cnt);
    gate_kernel<<<2048, 64, 0, stream>>>(hn, gw, gb, comb, idx0, cnt, tok_list);
    prefix_kernel<<<1, 64, 0, stream>>>(cnt, offs);

    if (big) {
        // MERGED routed+shared silu GEMM: routed mid -> amid; shared mid -> smid.
        mgemm2m<<<dim3(64, 16, 9), 256, 0, stream>>>(
            hn, ew1, ew3, eb1, eb3, sw1, sw3, sb1, sb3,
            amid, smid, 1024, tok_list, cnt, offs);
        // MERGED final GEMMs: z=0 shared-out full-K (writes sh, no reducek),
        // z=1..8 routed-out scatter (writes y0/y1).
        mgemmF<<<dim3(16, 16, 9), 256, 0, stream>>>(
            amid, smid, ew2, eb2, sw2, sb2, y0, y1, sh,
            tok_list, cnt, offs, comb, idx0);
    } else {
        // Fallback: sequential, amid reused routed->shared
        mgemm2<AM_GATHER><<<dim3(32, 16, 8), 256, 0, stream>>>(
            hn, ew1, ew3, eb1, eb3, amid, 2048, FF, 1024, tok_list, cnt, offs);
        mgemm<EPI_SCATTER, AM_GROUP, 1, 1><<<dim3(16, 16, 8), 256, 0, stream>>>(
            amid, ew2, nullptr, nullptr, eb2, nullptr, nullptr, nullptr, y0, nullptr, nullptr,
            2048, DD, FF, tok_list, cnt, offs, comb, idx0, y1);
        mgemm2<AM_DENSE><<<dim3(64, 16), 256, 0, stream>>>(
            hn, sw1, sw3, sb1, sb3, amid, 2048, FSH2, 1024, nullptr, nullptr, nullptr);
        mgemm<EPI_PLAIN, AM_DENSE, 1, 1><<<dim3(16, 16), 256, 0, stream>>>(
            amid, sw2, nullptr, nullptr, sb2, nullptr, nullptr, nullptr, sh, nullptr, nullptr,
            2048, DD, FSH2, NUL6);
    }
    final_kernel<<<2048, 256, 0, stream>>>(x2, y0, y1, sh, (float*)d_out);
}

// Round 23
// 551.593 us; speedup vs baseline: 1.0075x; 1.0075x over previous
//
#include <hip/hip_runtime.h>
#include <hip/hip_bf16.h>

// Shapes (fixed by the problem)
#define BB 2
#define SS 1024
#define DD 1024
#define HH 16
#define DKV 64
#define EE 8
#define FF 2048
#define FSH2 4096

typedef __attribute__((ext_vector_type(8))) short bf16x8;   // 8 bf16 = 4 VGPR (MFMA A/B frag)
typedef __attribute__((ext_vector_type(4))) float f32x4;    // MFMA C/D frag

#define EPI_PLAIN 0
#define EPI_SCATTER 2
#define AM_DENSE 0
#define AM_GATHER 1
#define AM_GROUP 2

__device__ inline unsigned pack_bf2(float lo, float hi) {
    __hip_bfloat162 h = __float22bfloat162_rn(float2{lo, hi});
    union { __hip_bfloat162 h2; unsigned u; } c; c.h2 = h; return c.u;
}
__device__ inline unsigned short bf16_1(float x) {
    union { __hip_bfloat16 b; unsigned short u; } c;
    c.b = __float2bfloat16(x); return c.u;
}

// ------------------------------------------------------------------
// bf16-MFMA GEMM, 128x64 tile, BK=32, 256 threads (4 waves as 2x2).
// DEPTH-4 software pipeline. Raw s_barrier (no vmcnt drain).
// B LDS layout [k-slot][col]. (Round-22 dbuf single-barrier variant was
// neutral -> reverted to this proven 2-barrier structure.)
// ------------------------------------------------------------------
#define LOADT(s, k0) {                                                        \
    const float4* ap4 = (const float4*)(Ap + (k0));                           \
    pa##s##_0 = ap4[0]; pa##s##_1 = ap4[1];                                   \
    pa##s##_2 = ap4[2]; pa##s##_3 = ap4[3];                                   \
    const float* wp = Wcol + (size_t)((k0) + kg * 8) * N;                     \
    _Pragma("unroll")                                                         \
    for (int j = 0; j < 8; ++j) pb##s[j] = wp[(size_t)j * N];                 \
}
#define STAGET(s) {                                                           \
    uint4 aw0, aw1;                                                           \
    aw0.x = pack_bf2(pa##s##_0.x, pa##s##_0.y);                               \
    aw0.y = pack_bf2(pa##s##_0.z, pa##s##_0.w);                               \
    aw0.z = pack_bf2(pa##s##_1.x, pa##s##_1.y);                               \
    aw0.w = pack_bf2(pa##s##_1.z, pa##s##_1.w);                               \
    aw1.x = pack_bf2(pa##s##_2.x, pa##s##_2.y);                               \
    aw1.y = pack_bf2(pa##s##_2.z, pa##s##_2.w);                               \
    aw1.z = pack_bf2(pa##s##_3.x, pa##s##_3.y);                               \
    aw1.w = pack_bf2(pa##s##_3.z, pa##s##_3.w);                               \
    *(uint4*)&As[ar * 40 + ac] = aw0;                                         \
    *(uint4*)&As[ar * 40 + ac + 8] = aw1;                                     \
    uint4 bw;                                                                 \
    bw.x = pack_bf2(pb##s[0], pb##s[1]);  bw.y = pack_bf2(pb##s[2], pb##s[3]);\
    bw.z = pack_bf2(pb##s[4], pb##s[5]);  bw.w = pack_bf2(pb##s[6], pb##s[7]);\
    *(uint4*)&Bs[kg * 512 + bn * 8] = bw;                                     \
}
#define MFMAT() {                                                             \
    bf16x8 af[4], bfr[2];                                                     \
    _Pragma("unroll")                                                         \
    for (int m = 0; m < 4; ++m) {                                             \
        int row = wr * 64 + m * 16 + ll;                                      \
        af[m] = *(const bf16x8*)&As[row * 40 + lh * 8];                       \
    }                                                                         \
    _Pragma("unroll")                                                         \
    for (int n = 0; n < 2; ++n) {                                             \
        int col = wc * 32 + n * 16 + ll;                                      \
        bfr[n] = *(const bf16x8*)&Bs[lh * 512 + col * 8];                     \
    }                                                                         \
    _Pragma("unroll")                                                         \
    for (int m = 0; m < 4; ++m)                                               \
        _Pragma("unroll")                                                     \
        for (int n = 0; n < 2; ++n)                                           \
            acc[m][n] = __builtin_amdgcn_mfma_f32_16x16x32_bf16(af[m], bfr[n], acc[m][n], 0, 0, 0); \
}
#define PHASET(s, nx) {                                                       \
    STAGET(s)                                                                 \
    if ((nx) < NT) LOADT(s, (nx) << 5)                                        \
    asm volatile("s_waitcnt lgkmcnt(0)\n\ts_barrier" ::: "memory");           \
    MFMAT()                                                                   \
    asm volatile("s_barrier" ::: "memory");                                   \
}

template<int EPI, int AMODE, int NSEL, int SPLITK>
__global__ __launch_bounds__(256, 2) void mgemm(
    const float* __restrict__ A,
    const float* __restrict__ W0, const float* __restrict__ W1p, const float* __restrict__ W2p,
    const float* __restrict__ b0, const float* __restrict__ b1p, const float* __restrict__ b2p,
    const float* __restrict__ addsrc,
    float* __restrict__ C0, float* __restrict__ C1p, float* __restrict__ C2p,
    int M, int N, int K,
    const int* __restrict__ tok_list, const int* __restrict__ cnt,
    const int* __restrict__ offs, const float* __restrict__ comb,
    const int* __restrict__ idx0, float* __restrict__ y1)
{
    __shared__ __align__(16) unsigned short As[128 * 40];   // 10 KB
    __shared__ __align__(16) unsigned short Bs[64 * 32];    // 4 KB, [slot][col]
    __shared__ int rows_s[128];
    const int t = threadIdx.x;
    const float* W = W0; const float* bias = b0; float* C = C0;
    if (NSEL == 3) {
        if (blockIdx.z == 1) { W = W1p; bias = b1p; C = C1p; }
        else if (blockIdx.z == 2) { W = W2p; bias = b2p; C = C2p; }
    }
    const int e = (AMODE != AM_DENSE) ? blockIdx.z : 0;
    int ne = M, base = 0;
    if (AMODE != AM_DENSE) {
        ne = cnt[e];
        base = offs[e];
        if ((int)blockIdx.y * 128 >= ne) return;   // uniform exit, before any barrier
        W += (size_t)e * K * N;
        bias += (size_t)e * N;
    }
    const int m0 = blockIdx.y * 128;
    const int n0 = blockIdx.x * 64;
    if (AMODE == AM_GATHER) {
        if (t < 128) {
            int li = m0 + t; if (li >= ne) li = ne - 1;
            rows_s[t] = tok_list[e * 2048 + li];
        }
        __syncthreads();
    }
    const int ar = t >> 1;
    const int ac = (t & 1) * 16;
    const int bn = t & 63;          // B col within tile
    const int kg = t >> 6;          // B k-group (8 rows each)
    long arow;
    if (AMODE == AM_DENSE) arow = m0 + ar;
    else if (AMODE == AM_GATHER) arow = rows_s[ar];
    else { int li = m0 + ar; if (li >= ne) li = ne - 1; arow = base + li; }
    const int Kc = (SPLITK > 1) ? (K / SPLITK) : K;
    const size_t koff = (SPLITK > 1) ? (size_t)blockIdx.z * Kc : 0;
    const float* Ap = A + (size_t)arow * K + ac + koff;
    const float* Wcol = W + koff * N + n0 + bn;
    const int l = t & 63, w = t >> 6;
    const int wr = w >> 1, wc = w & 1;
    const int lh = l >> 4, ll = l & 15;
    f32x4 acc[4][2];
#pragma unroll
    for (int i = 0; i < 4; ++i)
#pragma unroll
        for (int j = 0; j < 2; ++j) acc[i][j] = f32x4{0.f, 0.f, 0.f, 0.f};

    const int NT = Kc >> 5;   // 8/32/64/128 for shapes used here: all % 4 == 0
    float4 pa0_0, pa0_1, pa0_2, pa0_3; float pb0[8];
    float4 pa1_0, pa1_1, pa1_2, pa1_3; float pb1[8];
    float4 pa2_0, pa2_1, pa2_2, pa2_3; float pb2[8];
    float4 pa3_0, pa3_1, pa3_2, pa3_3; float pb3[8];
    LOADT(0, 0)
    LOADT(1, 32)
    LOADT(2, 64)
    LOADT(3, 96)
    for (int it = 0; it < NT; it += 4) {
        PHASET(0, it + 4)
        PHASET(1, it + 5)
        PHASET(2, it + 6)
        PHASET(3, it + 7)
    }

#pragma unroll
    for (int m = 0; m < 4; ++m) {
#pragma unroll
        for (int n = 0; n < 2; ++n) {
            int colg = n0 + wc * 32 + n * 16 + ll;
            float bvv = (SPLITK > 1) ? 0.f : bias[colg];
#pragma unroll
            for (int j = 0; j < 4; ++j) {
                int li = m0 + wr * 64 + m * 16 + lh * 4 + j;
                float v = acc[m][n][j] + bvv;
                if (SPLITK > 1) {
                    C[(size_t)blockIdx.z * M * N + (size_t)li * N + colg] = v;
                } else if (EPI == EPI_PLAIN) {
                    if (AMODE == AM_DENSE) {
                        if (addsrc) v += addsrc[(size_t)li * N + colg];
                        C[(size_t)li * N + colg] = v;
                    } else {
                        if (li < ne) C[(size_t)(base + li) * N + colg] = v;
                    }
                } else {  // EPI_SCATTER (AM_GROUP)
                    if (li < ne) {
                        int tok = tok_list[e * 2048 + li];
                        float wgt = comb[tok * 8 + e];
                        float* dst = (idx0[tok] == e) ? C : y1;
                        dst[(size_t)tok * N + colg] = wgt * v;
                    }
                }
            }
        }
    }
}

// ------------------------------------------------------------------
// MERGED final GEMMs: z==0 -> shared-out sw2 (full K=4096, dense, writes sh);
// z==1..8 -> routed-out expert z-1 (K=2048, comb-weighted scatter to y0/y1).
// ------------------------------------------------------------------
__global__ __launch_bounds__(256, 2) void mgemmF(
    const float* __restrict__ Amid,   // routed mid
    const float* __restrict__ Smid,   // shared mid
    const float* __restrict__ W2r, const float* __restrict__ B2r,
    const float* __restrict__ W2s, const float* __restrict__ B2s,
    float* __restrict__ y0, float* __restrict__ y1, float* __restrict__ sh,
    const int* __restrict__ tok_list, const int* __restrict__ cnt,
    const int* __restrict__ offs, const float* __restrict__ comb,
    const int* __restrict__ idx0)
{
    __shared__ __align__(16) unsigned short As[128 * 40];
    __shared__ __align__(16) unsigned short Bs[64 * 32];    // [slot][col]
    const int t = threadIdx.x;
    const int z = blockIdx.z;
    const bool sh_mode = (z == 0);
    const int e = sh_mode ? 0 : (z - 1);
    const int N = DD;
    int K, ne, base;
    const float *A, *W, *bias;
    if (sh_mode) {
        K = FSH2; ne = 2048; base = 0;
        A = Smid; W = W2s; bias = B2s;
    } else {
        K = FF;
        ne = cnt[e];
        base = offs[e];
        if ((int)blockIdx.y * 128 >= ne) return;   // uniform exit
        A = Amid;
        W = W2r + (size_t)e * K * N;
        bias = B2r + (size_t)e * N;
    }
    const int m0 = blockIdx.y * 128;
    const int n0 = blockIdx.x * 64;
    const int ar = t >> 1;
    const int ac = (t & 1) * 16;
    const int bn = t & 63;
    const int kg = t >> 6;
    long arow;
    if (sh_mode) arow = m0 + ar;
    else { int li = m0 + ar; if (li >= ne) li = ne - 1; arow = base + li; }
    const float* Ap = A + (size_t)arow * K + ac;
    const float* Wcol = W + n0 + bn;
    const int l = t & 63, w = t >> 6;
    const int wr = w >> 1, wc = w & 1;
    const int lh = l >> 4, ll = l & 15;
    f32x4 acc[4][2];
#pragma unroll
    for (int i = 0; i < 4; ++i)
#pragma unroll
        for (int j = 0; j < 2; ++j) acc[i][j] = f32x4{0.f, 0.f, 0.f, 0.f};

    const int NT = K >> 5;   // 128 (shared) or 64 (routed): both % 4 == 0
    float4 pa0_0, pa0_1, pa0_2, pa0_3; float pb0[8];
    float4 pa1_0, pa1_1, pa1_2, pa1_3; float pb1[8];
    float4 pa2_0, pa2_1, pa2_2, pa2_3; float pb2[8];
    float4 pa3_0, pa3_1, pa3_2, pa3_3; float pb3[8];
    LOADT(0, 0)
    LOADT(1, 32)
    LOADT(2, 64)
    LOADT(3, 96)
    for (int it = 0; it < NT; it += 4) {
        PHASET(0, it + 4)
        PHASET(1, it + 5)
        PHASET(2, it + 6)
        PHASET(3, it + 7)
    }

#pragma unroll
    for (int m = 0; m < 4; ++m) {
#pragma unroll
        for (int n = 0; n < 2; ++n) {
            int colg = n0 + wc * 32 + n * 16 + ll;
            float bvv = bias[colg];
#pragma unroll
            for (int j = 0; j < 4; ++j) {
                int li = m0 + wr * 64 + m * 16 + lh * 4 + j;
                float v = acc[m][n][j] + bvv;
                if (sh_mode) {
                    sh[(size_t)li * N + colg] = v;
                } else {
                    if (li < ne) {
                        int tok = tok_list[e * 2048 + li];
                        float wgt = comb[tok * 8 + e];
                        float* dst = (idx0[tok] == e) ? y0 : y1;
                        dst[(size_t)tok * N + colg] = wgt * v;
                    }
                }
            }
        }
    }
}

// ------------------------------------------------------------------
// FUSED dual-B silu GEMM at BN=64: Out = silu(A@W1+b1)*(A@W3+b3).
// DEPTH-2 (92 VGPR optimum). B1s/B3s in [slot][col] layout.
// ------------------------------------------------------------------
#define LOAD2T(s, k0) {                                                       \
    const float4* ap4 = (const float4*)(Ap + (k0));                           \
    pa##s##_0 = ap4[0]; pa##s##_1 = ap4[1];                                   \
    pa##s##_2 = ap4[2]; pa##s##_3 = ap4[3];                                   \
    const float* wp1 = W1col + (size_t)((k0) + kg * 8) * N;                   \
    const float* wp3 = W3col + (size_t)((k0) + kg * 8) * N;                   \
    _Pragma("unroll")                                                         \
    for (int j = 0; j < 8; ++j) {                                             \
        pb1##s[j] = wp1[(size_t)j * N];                                       \
        pb3##s[j] = wp3[(size_t)j * N];                                       \
    }                                                                         \
}
#define STAGE2T(s) {                                                          \
    uint4 aw0, aw1;                                                           \
    aw0.x = pack_bf2(pa##s##_0.x, pa##s##_0.y);                               \
    aw0.y = pack_bf2(pa##s##_0.z, pa##s##_0.w);                               \
    aw0.z = pack_bf2(pa##s##_1.x, pa##s##_1.y);                               \
    aw0.w = pack_bf2(pa##s##_1.z, pa##s##_1.w);                               \
    aw1.x = pack_bf2(pa##s##_2.x, pa##s##_2.y);                               \
    aw1.y = pack_bf2(pa##s##_2.z, pa##s##_2.w);                               \
    aw1.z = pack_bf2(pa##s##_3.x, pa##s##_3.y);                               \
    aw1.w = pack_bf2(pa##s##_3.z, pa##s##_3.w);                               \
    *(uint4*)&As[ar * 40 + ac] = aw0;                                         \
    *(uint4*)&As[ar * 40 + ac + 8] = aw1;                                     \
    uint4 bw;                                                                 \
    bw.x = pack_bf2(pb1##s[0], pb1##s[1]);  bw.y = pack_bf2(pb1##s[2], pb1##s[3]); \
    bw.z = pack_bf2(pb1##s[4], pb1##s[5]);  bw.w = pack_bf2(pb1##s[6], pb1##s[7]); \
    *(uint4*)&B1s[kg * 512 + bn * 8] = bw;                                    \
    bw.x = pack_bf2(pb3##s[0], pb3##s[1]);  bw.y = pack_bf2(pb3##s[2], pb3##s[3]); \
    bw.z = pack_bf2(pb3##s[4], pb3##s[5]);  bw.w = pack_bf2(pb3##s[6], pb3##s[7]); \
    *(uint4*)&B3s[kg * 512 + bn * 8] = bw;                                    \
}
#define MFMA2T() {                                                            \
    bf16x8 af[4], bfr[2];                                                     \
    _Pragma("unroll")                                                         \
    for (int m = 0; m < 4; ++m) {                                             \
        int row = wr * 64 + m * 16 + ll;                                      \
        af[m] = *(const bf16x8*)&As[row * 40 + lh * 8];                       \
    }                                                                         \
    _Pragma("unroll")                                                         \
    for (int n = 0; n < 2; ++n) {                                             \
        int col = wc * 32 + n * 16 + ll;                                      \
        bfr[n] = *(const bf16x8*)&B1s[lh * 512 + col * 8];                    \
    }                                                                         \
    _Pragma("unroll")                                                         \
    for (int m = 0; m < 4; ++m)                                               \
        _Pragma("unroll")                                                     \
        for (int n = 0; n < 2; ++n)                                           \
            acc1[m][n] = __builtin_amdgcn_mfma_f32_16x16x32_bf16(af[m], bfr[n], acc1[m][n], 0, 0, 0); \
    _Pragma("unroll")                                                         \
    for (int n = 0; n < 2; ++n) {                                             \
        int col = wc * 32 + n * 16 + ll;                                      \
        bfr[n] = *(const bf16x8*)&B3s[lh * 512 + col * 8];                    \
    }                                                                         \
    _Pragma("unroll")                                                         \
    for (int m = 0; m < 4; ++m)                                               \
        _Pragma("unroll")                                                     \
        for (int n = 0; n < 2; ++n)                                           \
            acc3[m][n] = __builtin_amdgcn_mfma_f32_16x16x32_bf16(af[m], bfr[n], acc3[m][n], 0, 0, 0); \
}
#define PHASE2T(s, nx) {                                                      \
    STAGE2T(s)                                                                \
    if ((nx) < NT) LOAD2T(s, (nx) << 5)                                       \
    asm volatile("s_waitcnt lgkmcnt(0)\n\ts_barrier" ::: "memory");           \
    MFMA2T()                                                                  \
    asm volatile("s_barrier" ::: "memory");                                   \
}

#define MGEMM2_BODY(GATED) {                                                  \
    const int l = t & 63, w = t >> 6;                                         \
    const int wr = w >> 1, wc = w & 1;                                        \
    const int lh = l >> 4, ll = l & 15;                                       \
    f32x4 acc1[4][2], acc3[4][2];                                             \
    _Pragma("unroll")                                                         \
    for (int i = 0; i < 4; ++i)                                               \
        _Pragma("unroll")                                                     \
        for (int j = 0; j < 2; ++j) {                                         \
            acc1[i][j] = f32x4{0.f, 0.f, 0.f, 0.f};                           \
            acc3[i][j] = f32x4{0.f, 0.f, 0.f, 0.f};                           \
        }                                                                     \
    const int NT = K >> 5;                                                    \
    float4 pa0_0, pa0_1, pa0_2, pa0_3; float pb10[8], pb30[8];                \
    float4 pa1_0, pa1_1, pa1_2, pa1_3; float pb11[8], pb31[8];                \
    LOAD2T(0, 0)                                                              \
    LOAD2T(1, 32)                                                             \
    for (int it = 0; it < NT; it += 2) {                                      \
        PHASE2T(0, it + 2)                                                    \
        PHASE2T(1, it + 3)                                                    \
    }                                                                         \
    _Pragma("unroll")                                                         \
    for (int m = 0; m < 4; ++m) {                                             \
        _Pragma("unroll")                                                     \
        for (int n = 0; n < 2; ++n) {                                         \
            int colg = n0 + wc * 32 + n * 16 + ll;                            \
            float bv1 = b1[colg], bv3 = b3[colg];                             \
            _Pragma("unroll")                                                 \
            for (int j = 0; j < 4; ++j) {                                     \
                int li = m0 + wr * 64 + m * 16 + lh * 4 + j;                  \
                if (GATED && li >= ne) continue;                              \
                float a = acc1[m][n][j] + bv1;                                \
                float g = acc3[m][n][j] + bv3;                                \
                float sil = a / (1.0f + __expf(-a));                          \
                size_t off = (size_t)(base + li) * N + colg;                  \
                Out[off] = sil * g;                                           \
            }                                                                 \
        }                                                                     \
    }                                                                         \
}

template<int AMODE>
__global__ __launch_bounds__(256, 2) void mgemm2(
    const float* __restrict__ A,
    const float* __restrict__ W1, const float* __restrict__ W3,
    const float* __restrict__ B1, const float* __restrict__ B3,
    float* __restrict__ Out, int M, int N, int K,
    const int* __restrict__ tok_list, const int* __restrict__ cnt,
    const int* __restrict__ offs)
{
    __shared__ __align__(16) unsigned short As[128 * 40];   // 10 KB
    __shared__ __align__(16) unsigned short B1s[64 * 32];   // 4 KB [slot][col]
    __shared__ __align__(16) unsigned short B3s[64 * 32];   // 4 KB [slot][col]
    __shared__ int rows_s[128];
    const int t = threadIdx.x;
    const int e = (AMODE == AM_GATHER) ? blockIdx.z : 0;
    int ne = M, base = 0;
    const float *w1 = W1, *w3 = W3, *b1 = B1, *b3 = B3;
    if (AMODE == AM_GATHER) {
        ne = cnt[e];
        base = offs[e];
        if ((int)blockIdx.y * 128 >= ne) return;   // uniform exit
        w1 += (size_t)e * K * N; w3 += (size_t)e * K * N;
        b1 += (size_t)e * N;     b3 += (size_t)e * N;
    }
    const int m0 = blockIdx.y * 128;
    const int n0 = blockIdx.x * 64;
    if (AMODE == AM_GATHER) {
        if (t < 128) {
            int li = m0 + t; if (li >= ne) li = ne - 1;
            rows_s[t] = tok_list[e * 2048 + li];
        }
        __syncthreads();
    }
    const int ar = t >> 1;
    const int ac = (t & 1) * 16;
    const int bn = t & 63;
    const int kg = t >> 6;
    long arow = (AMODE == AM_GATHER) ? (long)rows_s[ar] : (long)(m0 + ar);
    const float* Ap = A + (size_t)arow * K + ac;
    const float* W1col = w1 + n0 + bn;
    const float* W3col = w3 + n0 + bn;
    if (AMODE == AM_GATHER) { MGEMM2_BODY(1) } else { MGEMM2_BODY(0) }
}

// MERGED routed+shared silu GEMM: z<8 -> routed expert z (x<FF/64 only),
// z==8 -> shared dense (full x).
__global__ __launch_bounds__(256, 2) void mgemm2m(
    const float* __restrict__ A,
    const float* __restrict__ W1r, const float* __restrict__ W3r,
    const float* __restrict__ B1r, const float* __restrict__ B3r,
    const float* __restrict__ W1sh, const float* __restrict__ W3sh,
    const float* __restrict__ B1sh, const float* __restrict__ B3sh,
    float* __restrict__ OutR, float* __restrict__ OutS, int K,
    const int* __restrict__ tok_list, const int* __restrict__ cnt,
    const int* __restrict__ offs)
{
    __shared__ __align__(16) unsigned short As[128 * 40];
    __shared__ __align__(16) unsigned short B1s[64 * 32];   // [slot][col]
    __shared__ __align__(16) unsigned short B3s[64 * 32];   // [slot][col]
    __shared__ int rows_s[128];
    const int t = threadIdx.x;
    const int z = blockIdx.z;
    const bool routed = (z < 8);
    int N, ne, base;
    const float *w1, *w3, *b1, *b3;
    float* Out;
    if (routed) {
        if ((int)blockIdx.x >= FF / 64) return;       // uniform
        N = FF;
        ne = cnt[z];
        base = offs[z];
        if ((int)blockIdx.y * 128 >= ne) return;      // uniform
        w1 = W1r + (size_t)z * K * N; w3 = W3r + (size_t)z * K * N;
        b1 = B1r + (size_t)z * N;     b3 = B3r + (size_t)z * N;
        Out = OutR;
    } else {
        N = FSH2;
        ne = 2048;
        base = 0;
        w1 = W1sh; w3 = W3sh; b1 = B1sh; b3 = B3sh;
        Out = OutS;
    }
    const int m0 = blockIdx.y * 128;
    const int n0 = blockIdx.x * 64;
    if (routed) {
        if (t < 128) {
            int li = m0 + t; if (li >= ne) li = ne - 1;
            rows_s[t] = tok_list[z * 2048 + li];
        }
        __syncthreads();
    }
    const int ar = t >> 1;
    const int ac = (t & 1) * 16;
    const int bn = t & 63;
    const int kg = t >> 6;
    long arow = routed ? (long)rows_s[ar] : (long)(m0 + ar);
    const float* Ap = A + (size_t)arow * K + ac;
    const float* W1col = w1 + n0 + bn;
    const float* W3col = w3 + n0 + bn;
    if (routed) { MGEMM2_BODY(1) } else { MGEMM2_BODY(0) }
}

// ---------------------------------------------------------------- FUSED reduce + LayerNorm
// Block b == row b (256 threads x float4 = 1024 floats). Partial-sum order
// identical to the old reducek; ln reduction identical to ln_kernel ->
// bit-identical x2 and hn. Saves one launch + an 8MB x2 re-read.
__global__ __launch_bounds__(256) void reduceln(const float* __restrict__ P, int ns,
                                                const float* __restrict__ bias,
                                                const float* __restrict__ addsrc,
                                                float* __restrict__ x2out,
                                                const float* __restrict__ lw,
                                                float* __restrict__ hnout) {
    __shared__ float red[4], red2[4];
    const int row = blockIdx.x;
    const int t = threadIdx.x;
    size_t i = (size_t)row * 256 + t;                 // float4 index (N=1024)
    const size_t MN4 = (size_t)2048 * 256;
    float4 s = ((const float4*)P)[i];
    for (int sl = 1; sl < ns; ++sl) {
        float4 p = ((const float4*)P)[i + (size_t)sl * MN4];
        s.x += p.x; s.y += p.y; s.z += p.z; s.w += p.w;
    }
    float4 b = ((const float4*)bias)[t];
    s.x += b.x; s.y += b.y; s.z += b.z; s.w += b.w;
    float4 a = ((const float4*)addsrc)[i];
    s.x += a.x; s.y += a.y; s.z += a.z; s.w += a.w;
    ((float4*)x2out)[i] = s;
    // layernorm on s (same reduction tree as ln_kernel)
    float sum = s.x + s.y + s.z + s.w;
    float q = s.x * s.x + s.y * s.y + s.z * s.z + s.w * s.w;
    for (int o = 32; o; o >>= 1) { sum += __shfl_down(sum, o); q += __shfl_down(q, o); }
    if ((t & 63) == 0) { red[t >> 6] = sum; red2[t >> 6] = q; }
    __syncthreads();
    float S = red[0] + red[1] + red[2] + red[3];
    float Q = red2[0] + red2[1] + red2[2] + red2[3];
    float mu = S * (1.0f / DD);
    float var = Q * (1.0f / DD) - mu * mu;
    float inv = rsqrtf(var + 1e-8f);
    float4 wv = ((const float4*)lw)[t];
    float4 o4;
    o4.x = (s.x - mu) * inv * wv.x;
    o4.y = (s.y - mu) * inv * wv.y;
    o4.z = (s.z - mu) * inv * wv.z;
    o4.w = (s.w - mu) * inv * wv.w;
    ((float4*)(hnout + (size_t)row * DD))[t] = o4;
}

// ---------------------------------------------------------------- LayerNorm
__global__ __launch_bounds__(256) void ln_kernel(const float* __restrict__ x,
                                                 const float* __restrict__ w,
                                                 float* __restrict__ y) {
    __shared__ float red[4], red2[4];
    const int row = blockIdx.x;
    const int t = threadIdx.x;
    const float4* xr = (const float4*)(x + (size_t)row * DD);
    float4 v = xr[t];
    float s = v.x + v.y + v.z + v.w;
    float q = v.x * v.x + v.y * v.y + v.z * v.z + v.w * v.w;
    for (int o = 32; o; o >>= 1) { s += __shfl_down(s, o); q += __shfl_down(q, o); }
    if ((t & 63) == 0) { red[t >> 6] = s; red2[t >> 6] = q; }
    __syncthreads();
    float S = red[0] + red[1] + red[2] + red[3];
    float Q = red2[0] + red2[1] + red2[2] + red2[3];
    float mu = S * (1.0f / DD);
    float var = Q * (1.0f / DD) - mu * mu;
    float inv = rsqrtf(var + 1e-8f);
    const float4* wr = (const float4*)w;
    float4 wv = wr[t];
    float4 o4;
    o4.x = (v.x - mu) * inv * wv.x;
    o4.y = (v.y - mu) * inv * wv.y;
    o4.z = (v.z - mu) * inv * wv.z;
    o4.w = (v.w - mu) * inv * wv.w;
    ((float4*)(y + (size_t)row * DD))[t] = o4;
}

// ---------------------------------------------------------------- MFMA flash attention
// Q-tile 64 rows (wave owns 16): grid = (SS/64, B*H) = 512 blocks -> 2/CU.
__global__ __launch_bounds__(256) void attn_mfma(const float* __restrict__ Q,
                                                 const float* __restrict__ Kk,
                                                 const float* __restrict__ V,
                                                 const float* __restrict__ pe,
                                                 const float* __restrict__ mask,
                                                 const int* __restrict__ sp_ptr,
                                                 float* __restrict__ O) {
    __shared__ __align__(16) unsigned short Kt[64 * 64];    // 8 KB
    __shared__ __align__(16) unsigned short Vt[64 * 64];    // 8 KB
    __shared__ __align__(16) unsigned short Pl[4][16 * 64]; // 8 KB (16 rows/wave)
    const int t = threadIdx.x;
    const int w = t >> 6, l = t & 63;
    const int ll = l & 15, lh = l >> 4;
    const int bh = blockIdx.y;
    const int b = bh >> 4, h = bh & 15;
    const int q0 = blockIdx.x * 64;
    const int sp = sp_ptr[0];

    bf16x8 qf[2];
    {
        const float* qp = Q + (size_t)(b * SS + q0 + w * 16 + ll) * DD + h * 64 + lh * 8;
#pragma unroll
        for (int kk = 0; kk < 2; ++kk) {
            float4 x0 = *(const float4*)(qp + kk * 32);
            float4 x1 = *(const float4*)(qp + kk * 32 + 4);
            uint4 u;
            u.x = pack_bf2(x0.x * 0.125f, x0.y * 0.125f);
            u.y = pack_bf2(x0.z * 0.125f, x0.w * 0.125f);
            u.z = pack_bf2(x1.x * 0.125f, x1.y * 0.125f);
            u.w = pack_bf2(x1.z * 0.125f, x1.w * 0.125f);
            qf[kk] = *(bf16x8*)&u;
        }
    }
    f32x4 oacc[4];
#pragma unroll
    for (int n = 0; n < 4; ++n) oacc[n] = f32x4{0.f, 0.f, 0.f, 0.f};
    float mrun[4], lrun[4];
#pragma unroll
    for (int j = 0; j < 4; ++j) { mrun[j] = -3.0e38f; lrun[j] = 0.f; }

    const size_t pebase = (size_t)h * SS * SS + (size_t)sp;

    for (int kt0 = 0; kt0 < SS; kt0 += 64) {
        __syncthreads();
        {
            const int key = t >> 2, dg = (t & 3) * 16;
            const float* kp = Kk + (size_t)(b * SS + kt0 + key) * DD + h * 64 + dg;
            float4 k0 = *(const float4*)kp, k1 = *(const float4*)(kp + 4);
            float4 k2 = *(const float4*)(kp + 8), k3 = *(const float4*)(kp + 12);
            uint4 u0, u1;
            u0.x = pack_bf2(k0.x, k0.y); u0.y = pack_bf2(k0.z, k0.w);
            u0.z = pack_bf2(k1.x, k1.y); u0.w = pack_bf2(k1.z, k1.w);
            u1.x = pack_bf2(k2.x, k2.y); u1.y = pack_bf2(k2.z, k2.w);
            u1.z = pack_bf2(k3.x, k3.y); u1.w = pack_bf2(k3.z, k3.w);
            const int sw = (key & 7) << 4;
            *(uint4*)((char*)Kt + key * 128 + ((dg * 2) ^ sw)) = u0;
            *(uint4*)((char*)Kt + key * 128 + ((dg * 2 + 16) ^ sw)) = u1;
        }
        {
            const int kp2 = t & 31, vg = (t >> 5) * 8;
            const float* vp0 = V + (size_t)(b * SS + kt0 + 2 * kp2) * DD + h * 64 + vg;
            const float* vp1 = vp0 + DD;
            float4 a0 = *(const float4*)vp0, a1 = *(const float4*)(vp0 + 4);
            float4 b0 = *(const float4*)vp1, b1 = *(const float4*)(vp1 + 4);
            float va[8] = {a0.x, a0.y, a0.z, a0.w, a1.x, a1.y, a1.z, a1.w};
            float vb[8] = {b0.x, b0.y, b0.z, b0.w, b1.x, b1.y, b1.z, b1.w};
#pragma unroll
            for (int j = 0; j < 8; ++j) {
                int vd = vg + j;
                unsigned u = pack_bf2(va[j], vb[j]);
                *(unsigned*)((char*)Vt + vd * 128 + ((kp2 * 4) ^ ((vd & 7) << 4))) = u;
            }
        }
        __syncthreads();
        f32x4 sc[4];
#pragma unroll
        for (int n = 0; n < 4; ++n) sc[n] = f32x4{0.f, 0.f, 0.f, 0.f};
#pragma unroll
        for (int n = 0; n < 4; ++n) {
            const int key = n * 16 + ll;
            const int sw = (key & 7) << 4;
#pragma unroll
            for (int kk = 0; kk < 2; ++kk) {
                bf16x8 kf = *(const bf16x8*)((char*)Kt + key * 128 + ((kk * 64 + lh * 16) ^ sw));
                sc[n] = __builtin_amdgcn_mfma_f32_16x16x32_bf16(qf[kk], kf, sc[n], 0, 0, 0);
            }
        }
#pragma unroll
        for (int j = 0; j < 4; ++j) {
            const int qrow = q0 + w * 16 + lh * 4 + j;
            const float* per = pe + pebase + (size_t)(sp + qrow) * SS + kt0 + ll;
            const float* mar = mask + (size_t)qrow * SS + kt0 + ll;
#pragma unroll
            for (int n = 0; n < 4; ++n)
                sc[n][j] += per[n * 16] + mar[n * 16];
        }
#pragma unroll
        for (int j = 0; j < 4; ++j) {
            float mx = fmaxf(fmaxf(sc[0][j], sc[1][j]), fmaxf(sc[2][j], sc[3][j]));
#pragma unroll
            for (int o = 1; o < 16; o <<= 1) mx = fmaxf(mx, __shfl_xor(mx, o));
            float mnew = fmaxf(mrun[j], mx);
            float corr = __expf(mrun[j] - mnew);
            mrun[j] = mnew;
            float ssum = 0.f;
#pragma unroll
            for (int n = 0; n < 4; ++n) {
                float p = __expf(sc[n][j] - mnew);
                sc[n][j] = p;
                ssum += p;
            }
#pragma unroll
            for (int o = 1; o < 16; o <<= 1) ssum += __shfl_xor(ssum, o);
            lrun[j] = lrun[j] * corr + ssum;
#pragma unroll
            for (int n = 0; n < 4; ++n) oacc[n][j] *= corr;
        }
#pragma unroll
        for (int j = 0; j < 4; ++j) {
            const int lq = lh * 4 + j;
            const int sw = (lq & 7) << 4;
#pragma unroll
            for (int n = 0; n < 4; ++n) {
                const int key = n * 16 + ll;
                *(unsigned short*)((char*)Pl[w] + lq * 128 + ((key * 2) ^ sw)) =
                    bf16_1(sc[n][j]);
            }
        }
        asm volatile("s_waitcnt lgkmcnt(0)" ::: "memory");
        __builtin_amdgcn_sched_barrier(0);
#pragma unroll
        for (int kk = 0; kk < 2; ++kk) {
            const int lq = ll;
            bf16x8 pf = *(const bf16x8*)((char*)Pl[w] + lq * 128 +
                                         ((kk * 64 + lh * 16) ^ ((lq & 7) << 4)));
#pragma unroll
            for (int n = 0; n < 4; ++n) {
                const int vd = n * 16 + ll;
                bf16x8 vf = *(const bf16x8*)((char*)Vt + vd * 128 +
                                             ((kk * 64 + lh * 16) ^ ((vd & 7) << 4)));
                oacc[n] = __builtin_amdgcn_mfma_f32_16x16x32_bf16(pf, vf, oacc[n], 0, 0, 0);
            }
        }
    }
#pragma unroll
    for (int j = 0; j < 4; ++j) {
        const int qrow = q0 + w * 16 + lh * 4 + j;
        const float invl = 1.0f / lrun[j];
#pragma unroll
        for (int n = 0; n < 4; ++n)
            O[(size_t)(b * SS + qrow) * DD + h * 64 + n * 16 + ll] = oacc[n][j] * invl;
    }
}

// ---------------------------------------------------------------- Gating (f32 path)
__global__ __launch_bounds__(64) void gate_kernel(const float* __restrict__ hn,
                                                  const float* __restrict__ gw,
                                                  const float* __restrict__ gb,
                                                  float* __restrict__ comb,
                                                  int* __restrict__ idx0,
                                                  int* __restrict__ cnt,
                                                  int* __restrict__ tok_list) {
    __shared__ float lg[8];
    const int tok = blockIdx.x;
    const int lane = threadIdx.x;
    const int e = lane >> 3, chunk = lane & 7;
    const float* hr = hn + (size_t)tok * DD + chunk * 128;
    const float* gr = gw + (size_t)e * DD + chunk * 128;
    float p = 0.f;
    for (int j = 0; j < 128; ++j) p += hr[j] * gr[j];
    p += __shfl_down(p, 4, 8);
    p += __shfl_down(p, 2, 8);
    p += __shfl_down(p, 1, 8);
    if (chunk == 0) lg[e] = p + gb[e];
    __syncthreads();
    if (lane == 0) {
        float mx = lg[0];
        for (int i = 1; i < 8; ++i) mx = fmaxf(mx, lg[i]);
        float pr[8]; float ssum = 0.f;
        for (int i = 0; i < 8; ++i) { pr[i] = __expf(lg[i] - mx); ssum += pr[i]; }
        float is = 1.0f / ssum;
        for (int i = 0; i < 8; ++i) pr[i] *= is;
        int i1 = 0;
        for (int i = 1; i < 8; ++i) if (pr[i] > pr[i1]) i1 = i;
        int i2 = -1;
        for (int i = 0; i < 8; ++i) { if (i == i1) continue; if (i2 < 0 || pr[i] > pr[i2]) i2 = i; }
        float w0 = pr[i1], w1 = pr[i2];
        float nrm = 1.0f / (w0 + w1 + 1e-20f);
        w0 *= nrm; w1 *= nrm;
        for (int i = 0; i < 8; ++i) comb[tok * 8 + i] = 0.0f;
        comb[tok * 8 + i1] = w0;
        comb[tok * 8 + i2] = w1;
        idx0[tok] = i1;
        int s1 = atomicAdd(&cnt[i1], 1); tok_list[i1 * 2048 + s1] = tok;
        int s2 = atomicAdd(&cnt[i2], 1); tok_list[i2 * 2048 + s2] = tok;
    }
}

__global__ void init_cnt(int* cnt) { if (threadIdx.x < 8) cnt[threadIdx.x] = 0; }

__global__ void prefix_kernel(const int* __restrict__ cnt, int* __restrict__ offs) {
    if (threadIdx.x == 0) {
        int a = 0;
        for (int e = 0; e < 8; ++e) { offs[e] = a; a += cnt[e]; }
    }
}

// ---------------------------------------------------------------- Final sum
__global__ __launch_bounds__(256) void final_kernel(const float* __restrict__ x2,
                                                    const float* __restrict__ y0,
                                                    const float* __restrict__ y1,
                                                    const float* __restrict__ sh,
                                                    float* __restrict__ out) {
    size_t i = (size_t)blockIdx.x * 256 + threadIdx.x;
    float4 a = ((const float4*)x2)[i];
    float4 b = ((const float4*)y0)[i];
    float4 c = ((const float4*)y1)[i];
    float4 d = ((const float4*)sh)[i];
    float4 o;
    o.x = a.x + b.x + c.x + d.x;
    o.y = a.y + b.y + c.y + d.y;
    o.z = a.z + b.z + c.z + d.z;
    o.w = a.w + b.w + c.w + d.w;
    ((float4*)out)[i] = o;
}

#define NUL6 nullptr, nullptr, nullptr, nullptr, nullptr, nullptr

extern "C" void kernel_launch(void* const* d_in, const int* in_sizes, int n_in,
                              void* d_out, int out_size, void* d_ws, size_t ws_size,
                              hipStream_t stream) {
    const float* x   = (const float*)d_in[0];
    const int*   sp  = (const int*)d_in[1];
    const float* mask= (const float*)d_in[2];
    const float* pe  = (const float*)d_in[3];
    const float* anw = (const float*)d_in[4];
    const float* fnw = (const float*)d_in[5];
    const float* wq  = (const float*)d_in[6];  const float* bq  = (const float*)d_in[7];
    const float* wk  = (const float*)d_in[8];  const float* bk  = (const float*)d_in[9];
    const float* wv  = (const float*)d_in[10]; const float* bv  = (const float*)d_in[11];
    const float* wo  = (const float*)d_in[12]; const float* bo  = (const float*)d_in[13];
    const float* gw  = (const float*)d_in[14]; const float* gb  = (const float*)d_in[15];
    const float* ew1 = (const float*)d_in[16]; const float* eb1 = (const float*)d_in[17];
    const float* ew2 = (const float*)d_in[18]; const float* eb2 = (const float*)d_in[19];
    const float* ew3 = (const float*)d_in[20]; const float* eb3 = (const float*)d_in[21];
    const float* sw1 = (const float*)d_in[22]; const float* sb1 = (const float*)d_in[23];
    const float* sw2 = (const float*)d_in[24]; const float* sb2 = (const float*)d_in[25];
    const float* sw3 = (const float*)d_in[26]; const float* sb3 = (const float*)d_in[27];

    float* ws = (float*)d_ws;
    const size_t M2 = (size_t)2048 * 1024;   // 8 MB (2M floats) per slot
    float* comb = ws;                        // 2048*8
    int* idx0   = (int*)(ws + 16384);        // 2048
    int* cnt    = idx0 + 2048;
    int* offs   = cnt + 8;
    int* tok_list = offs + 8;                // 8*2048
    float* base = ws + 65536;
    float* xn   = base;
    float* q    = base + 1 * M2;
    float* kbuf = base + 2 * M2;
    float* vbuf = base + 3 * M2;
    float* x2   = base + 4 * M2;
    float* amid = base + 5 * M2;             // wo partials -> routed mid (slots 5-8)
    float* smid = base + 9 * M2;             // shared mid (slots 9-12, big path)
    const bool big = ws_size >= (size_t)(65536 + 13 * M2) * sizeof(float);
    float* o   = xn;
    float* hn  = q;
    float* y0  = xn;
    float* y1  = kbuf;
    float* sh  = vbuf;

    ln_kernel<<<2048, 256, 0, stream>>>(x, anw, xn);
    // QKV in one dispatch (z selects W/bias/C)
    mgemm<EPI_PLAIN, AM_DENSE, 3, 1><<<dim3(16, 16, 3), 256, 0, stream>>>(
        xn, wq, wk, wv, bq, bk, bv, nullptr, q, kbuf, vbuf,
        2048, 1024, 1024, NUL6);
    attn_mfma<<<dim3(SS / 64, BB * HH), 256, 0, stream>>>(q, kbuf, vbuf, pe, mask, sp, o);
    // wo: split-K4 into amid (free here), then FUSED reduce+residual+layernorm
    mgemm<EPI_PLAIN, AM_DENSE, 1, 4><<<dim3(16, 16, 4), 256, 0, stream>>>(
        o, wo, nullptr, nullptr, bo, nullptr, nullptr, nullptr, amid, nullptr, nullptr,
        2048, 1024, 1024, NUL6);
    reduceln<<<2048, 256, 0, stream>>>(amid, 4, bo, x, x2, fnw, hn);
    init_cnt<<<1, 64, 0, stream>>>(cnt);
    gate_kernel<<<2048, 64, 0, stream>>>(hn, gw, gb, comb, idx0, cnt, tok_list);
    prefix_kernel<<<1, 64, 0, stream>>>(cnt, offs);

    if (big) {
        // MERGED routed+shared silu GEMM: routed mid -> amid; shared mid -> smid.
        mgemm2m<<<dim3(64, 16, 9), 256, 0, stream>>>(
            hn, ew1, ew3, eb1, eb3, sw1, sw3, sb1, sb3,
            amid, smid, 1024, tok_list, cnt, offs);
        // MERGED final GEMMs: z=0 shared-out full-K (writes sh, no reducek),
        // z=1..8 routed-out scatter (writes y0/y1).
        mgemmF<<<dim3(16, 16, 9), 256, 0, stream>>>(
            amid, smid, ew2, eb2, sw2, sb2, y0, y1, sh,
            tok_list, cnt, offs, comb, idx0);
    } else {
        // Fallback: sequential, amid reused routed->shared
        mgemm2<AM_GATHER><<<dim3(32, 16, 8), 256, 0, stream>>>(
            hn, ew1, ew3, eb1, eb3, amid, 2048, FF, 1024, tok_list, cnt, offs);
        mgemm<EPI_SCATTER, AM_GROUP, 1, 1><<<dim3(16, 16, 8), 256, 0, stream>>>(
            amid, ew2, nullptr, nullptr, eb2, nullptr, nullptr, nullptr, y0, nullptr, nullptr,
            2048, DD, FF, tok_list, cnt, offs, comb, idx0, y1);
        mgemm2<AM_DENSE><<<dim3(64, 16), 256, 0, stream>>>(
            hn, sw1, sw3, sb1, sb3, amid, 2048, FSH2, 1024, nullptr, nullptr, nullptr);
        mgemm<EPI_PLAIN, AM_DENSE, 1, 1><<<dim3(16, 16), 256, 0, stream>>>(
            amid, sw2, nullptr, nullptr, sb2, nullptr, nullptr, nullptr, sh, nullptr, nullptr,
            2048, DD, FSH2, NUL6);
    }
    final_kernel<<<2048, 256, 0, stream>>>(x2, y0, y1, sh, (float*)d_out);
}